// Round 5
// baseline (1258.085 us; speedup 1.0000x reference)
//
#include <hip/hip_runtime.h>

#define EMB_D 128
#define SLOT_CAP 96   // max stored edges/slot; row degree ~Poisson(32), P(>96)≈0

// ---------- Pass 1: claim needed nodes. map[node] = slot+1, slot in [0,2B). ----------
__global__ void claim_kernel(const int* __restrict__ user_idx,
                             const int* __restrict__ item_idx,
                             int* __restrict__ node_map, int B, int U) {
    int t = blockIdx.x * blockDim.x + threadIdx.x;
    if (t >= 2 * B) return;
    int node = (t < B) ? user_idx[t] : (U + item_idx[t - B]);
    atomicCAS(&node_map[node], 0, t + 1);
}

__device__ __forceinline__ void slow_place(int slot, int c, float v,
        int* __restrict__ deg, int2* __restrict__ edge_buf,
        float* __restrict__ comp,
        const float* __restrict__ user_emb, const float* __restrict__ item_emb,
        int U) {
    int pos = atomicAdd(&deg[slot], 1);
    if (pos < SLOT_CAP) {
        edge_buf[(size_t)slot * SLOT_CAP + pos] = make_int2(c, __float_as_int(v));
    } else {  // ~never: exact fallback, comp pre-zeroed
        const float* src = (c < U) ? (user_emb + (size_t)c * EMB_D)
                                   : (item_emb + (size_t)(c - U) * EMB_D);
        float* dst = comp + (size_t)slot * EMB_D;
        for (int i = 0; i < EMB_D; ++i) atomicAdd(dst + i, v * src[i]);
    }
}

// ---------- Pass 2a: filter + wave-compact needed edges into a contiguous list. ----------
__global__ void compact_kernel(const float* __restrict__ vals,
                               const int* __restrict__ rows,
                               const int* __restrict__ cols,
                               const int* __restrict__ node_map,
                               int* __restrict__ cursor,
                               int* __restrict__ cslot,
                               int2* __restrict__ ccv,
                               int* __restrict__ deg,
                               int2* __restrict__ edge_buf,
                               float* __restrict__ comp,
                               const float* __restrict__ user_emb,
                               const float* __restrict__ item_emb,
                               int nnz, int U, int ccap) {
    int e = blockIdx.x * blockDim.x + threadIdx.x;
    int lane = threadIdx.x & 63;
    int s = 0;
    if (e < nnz) s = node_map[rows[e]];
    bool need = (s != 0);
    unsigned long long mask = __ballot(need);
    if (mask == 0) return;                 // wave-uniform
    int nact   = __popcll(mask);
    int leader = __ffsll((long long)mask) - 1;
    int base = 0;
    if (lane == leader) base = atomicAdd(cursor, nact);   // 1 atomic per wave
    base = __shfl(base, leader);
    if (need) {
        int prefix = __popcll(mask & ((1ull << lane) - 1));
        int idx = base + prefix;                          // contiguous across lanes
        int c   = cols[e];
        float v = vals[e];
        if (idx < ccap) {
            cslot[idx] = s - 1;
            ccv[idx]   = make_int2(c, __float_as_int(v));
        } else {  // capacity overflow (~never): place directly
            slow_place(s - 1, c, v, deg, edge_buf, comp, user_emb, item_emb, U);
        }
    }
}

// ---------- Pass 2b: bucket the compact list; every lane active. ----------
__global__ void bucket_kernel(const int* __restrict__ cslot,
                              const int2* __restrict__ ccv,
                              const int* __restrict__ cursor,
                              int* __restrict__ deg,
                              int2* __restrict__ edge_buf,
                              float* __restrict__ comp,
                              const float* __restrict__ user_emb,
                              const float* __restrict__ item_emb,
                              int U, int ccap) {
    int n = *cursor;
    if (n > ccap) n = ccap;
    int stride = gridDim.x * blockDim.x;
    for (int i = blockIdx.x * blockDim.x + threadIdx.x; i < n; i += stride) {
        int  slot = cslot[i];
        int2 cv   = ccv[i];
        int pos = atomicAdd(&deg[slot], 1);
        if (pos < SLOT_CAP) {
            edge_buf[(size_t)slot * SLOT_CAP + pos] = cv;
        } else {
            int c = cv.x;
            float v = __int_as_float(cv.y);
            const float* src = (c < U) ? (user_emb + (size_t)c * EMB_D)
                                       : (item_emb + (size_t)(c - U) * EMB_D);
            float* dst = comp + (size_t)slot * EMB_D;
            for (int k = 0; k < EMB_D; ++k) atomicAdd(dst + k, v * src[k]);
        }
    }
}

// ---------- Tier-B fallback: direct per-edge fill (round-3 style). ----------
__global__ void fill_kernel(const float* __restrict__ user_emb,
                            const float* __restrict__ item_emb,
                            const float* __restrict__ vals,
                            const int* __restrict__ rows,
                            const int* __restrict__ cols,
                            const int* __restrict__ node_map,
                            int* __restrict__ deg,
                            int2* __restrict__ edge_buf,
                            float* __restrict__ comp,
                            int nnz, int U) {
    int e = blockIdx.x * blockDim.x + threadIdx.x;
    if (e >= nnz) return;
    int s = node_map[rows[e]];
    if (s == 0) return;
    slow_place(s - 1, cols[e], vals[e], deg, edge_buf, comp, user_emb, item_emb, U);
}

// ---------- Pass 3: one wave per slot; edge list pre-loaded per-lane, shfl ----------
// broadcast (no memory dependence), 8 row-gathers in flight, register accumulate.
__global__ void gather_kernel(const float* __restrict__ user_emb,
                              const float* __restrict__ item_emb,
                              const int2* __restrict__ edge_buf,
                              const int* __restrict__ deg,
                              float* __restrict__ comp,
                              int nslots, int U) {
    int wid  = (blockIdx.x * blockDim.x + threadIdx.x) >> 6;
    int lane = threadIdx.x & 63;
    if (wid >= nslots) return;
    int d = deg[wid];
    bool ovf = (d > SLOT_CAP);
    int dc = ovf ? SLOT_CAP : d;
    const int2* eb = edge_buf + (size_t)wid * SLOT_CAP;
    float* dst = comp + (size_t)wid * EMB_D + lane * 2;

    int2 my_e = eb[lane];                      // lane i owns edge i (SLOT_CAP >= 64)
    int  myc  = my_e.x;
    const float* mybase = (myc < U) ? (user_emb + (size_t)myc * EMB_D)
                                    : (item_emb + (size_t)(myc - U) * EMB_D);
    unsigned long long mba = (unsigned long long)mybase;
    int   b_lo = (int)(unsigned)mba;
    int   b_hi = (int)(mba >> 32);
    float myv  = __int_as_float(my_e.y);

    float2 a[8];
#pragma unroll
    for (int k = 0; k < 8; ++k) a[k] = make_float2(0.f, 0.f);

    int n0 = dc < 64 ? dc : 64;
    for (int j = 0; j < n0; j += 8) {
        const float* p[8];
        float vv[8];
#pragma unroll
        for (int k = 0; k < 8; ++k) {
            int jj = (j + k < n0) ? (j + k) : (n0 - 1);   // wave-uniform
            int   lo = __shfl(b_lo, jj);
            int   hi = __shfl(b_hi, jj);
            float v  = __shfl(myv, jj);
            vv[k] = (j + k < n0) ? v : 0.f;               // mask tail
            p[k]  = (const float*)(((unsigned long long)(unsigned)hi << 32)
                                   | (unsigned)lo);
        }
        float2 x[8];
#pragma unroll
        for (int k = 0; k < 8; ++k) x[k] = *(const float2*)(p[k] + lane * 2);
#pragma unroll
        for (int k = 0; k < 8; ++k) {
            a[k].x = fmaf(vv[k], x[k].x, a[k].x);
            a[k].y = fmaf(vv[k], x[k].y, a[k].y);
        }
    }

    float2 tl = make_float2(0.f, 0.f);
    for (int j = 64; j < dc; ++j) {            // rare: degree in (64, SLOT_CAP]
        int2 ed = eb[j];
        int c = ed.x;
        float v = __int_as_float(ed.y);
        const float* src = (c < U) ? (user_emb + (size_t)c * EMB_D)
                                   : (item_emb + (size_t)(c - U) * EMB_D);
        float2 x = *(const float2*)(src + lane * 2);
        tl.x = fmaf(v, x.x, tl.x);
        tl.y = fmaf(v, x.y, tl.y);
    }

    float rx = ((a[0].x + a[1].x) + (a[2].x + a[3].x))
             + ((a[4].x + a[5].x) + (a[6].x + a[7].x)) + tl.x;
    float ry = ((a[0].y + a[1].y) + (a[2].y + a[3].y))
             + ((a[4].y + a[5].y) + (a[6].y + a[7].y)) + tl.y;
    if (ovf) { dst[0] += rx; dst[1] += ry; }  // overflow part already added atomically
    else     { dst[0] = rx;  dst[1] = ry; }   // includes d==0 -> store zeros
}

// ---------- Pass 4: per-pair fused gather + dot. One wave per output. ----------
__global__ void final_kernel(const float* __restrict__ user_emb,
                             const float* __restrict__ item_emb,
                             const int* __restrict__ user_idx,
                             const int* __restrict__ item_idx,
                             const int* __restrict__ node_map,
                             const float* __restrict__ comp,
                             float* __restrict__ out, int B, int U) {
    int wid  = (blockIdx.x * blockDim.x + threadIdx.x) >> 6;
    int lane = threadIdx.x & 63;
    if (wid >= B) return;
    int un  = user_idx[wid];
    int inn = item_idx[wid];
    int su  = node_map[un] - 1;
    int si  = node_map[U + inn] - 1;
    float2 eu = *(const float2*)(user_emb + (size_t)un * EMB_D + lane * 2);
    float2 ei = *(const float2*)(item_emb + (size_t)inn * EMB_D + lane * 2);
    float2 cu = *(const float2*)(comp + (size_t)su * EMB_D + lane * 2);
    float2 ci = *(const float2*)(comp + (size_t)si * EMB_D + lane * 2);
    float p = (eu.x + cu.x) * (ei.x + ci.x) + (eu.y + cu.y) * (ei.y + ci.y);
#pragma unroll
    for (int off = 32; off; off >>= 1) p += __shfl_down(p, off);
    if (lane == 0) out[wid] = 0.25f * p;
}

// ---------- Tier-C fallback (tiny ws): direct atomic scatter ----------
__global__ void scatter_kernel(const float* __restrict__ user_emb,
                               const float* __restrict__ item_emb,
                               const float* __restrict__ vals,
                               const int* __restrict__ rows,
                               const int* __restrict__ cols,
                               const int* __restrict__ node_map,
                               float* __restrict__ comp,
                               int nnz, int U) {
    int e = blockIdx.x * blockDim.x + threadIdx.x;
    int lane = threadIdx.x & 63;
    int s = 0; int c = 0; float v = 0.f;
    if (e < nnz) {
        int r = rows[e];
        s = node_map[r];
        if (s != 0) { c = cols[e]; v = vals[e]; }
    }
    unsigned long long mask = __ballot(s != 0);
    while (mask) {
        int j = __ffsll((long long)mask) - 1;
        mask &= mask - 1;
        int   cj    = __shfl(c, j);
        float vj    = __shfl(v, j);
        int   slotj = __shfl(s, j) - 1;
        const float* src = (cj < U) ? (user_emb + (size_t)cj * EMB_D)
                                    : (item_emb + (size_t)(cj - U) * EMB_D);
        float2 x = *(const float2*)(src + lane * 2);
        float* dst = comp + (size_t)slotj * EMB_D + lane * 2;
        atomicAdd(dst,     x.x * vj);
        atomicAdd(dst + 1, x.y * vj);
    }
}

extern "C" void kernel_launch(void* const* d_in, const int* in_sizes, int n_in,
                              void* d_out, int out_size, void* d_ws, size_t ws_size,
                              hipStream_t stream) {
    const float* user_emb = (const float*)d_in[0];
    const float* item_emb = (const float*)d_in[1];
    const float* adj_vals = (const float*)d_in[2];
    const int*   adj_rows = (const int*)d_in[3];
    const int*   adj_cols = (const int*)d_in[4];
    const int*   user_idx = (const int*)d_in[5];
    const int*   item_idx = (const int*)d_in[6];
    float* out = (float*)d_out;

    int U   = in_sizes[0] / EMB_D;
    int I   = in_sizes[1] / EMB_D;
    int N   = U + I;
    int nnz = in_sizes[2];
    int B   = in_sizes[5];
    int S   = 2 * B;                       // slot count

    // Workspace: [comp S*D f32][map N i32][deg S i32 + cursor][edge_buf S*CAP int2]
    //            [cslot ccap i32][ccv ccap int2]
    size_t comp_bytes = (size_t)S * EMB_D * sizeof(float);
    size_t map_bytes  = ((size_t)N * sizeof(int) + 15) & ~(size_t)15;
    size_t deg_bytes  = (((size_t)S + 4) * sizeof(int) + 15) & ~(size_t)15;
    size_t edge_bytes = (size_t)S * SLOT_CAP * sizeof(int2);
    size_t fixed      = comp_bytes + map_bytes + deg_bytes + edge_bytes;

    float* comp     = (float*)d_ws;
    int*   node_map = (int*)((char*)d_ws + comp_bytes);
    int*   deg      = (int*)((char*)d_ws + comp_bytes + map_bytes);
    int*   cursor   = deg + S;
    int2*  edge_buf = (int2*)((char*)d_ws + comp_bytes + map_bytes + deg_bytes);

    long long ccap = 0;
    if (ws_size > fixed + 64) {
        ccap = (long long)((ws_size - fixed - 64) / 12);
        if (ccap > nnz) ccap = nnz;
    }
    int*  cslot = (int*)((char*)d_ws + fixed);
    int2* ccv   = (int2*)((char*)d_ws + fixed + (((size_t)ccap * 4 + 15) & ~(size_t)15));

    if (ccap >= (1 << 20)) {
        // Tier A: compact + bucket
        hipMemsetAsync(d_ws, 0, comp_bytes + map_bytes + deg_bytes, stream);
        claim_kernel<<<(S + 255) / 256, 256, 0, stream>>>(user_idx, item_idx,
                                                          node_map, B, U);
        compact_kernel<<<(nnz + 255) / 256, 256, 0, stream>>>(
            adj_vals, adj_rows, adj_cols, node_map, cursor, cslot, ccv,
            deg, edge_buf, comp, user_emb, item_emb, nnz, U, (int)ccap);
        bucket_kernel<<<2048, 256, 0, stream>>>(cslot, ccv, cursor, deg, edge_buf,
                                                comp, user_emb, item_emb, U, (int)ccap);
        gather_kernel<<<(S * 64 + 255) / 256, 256, 0, stream>>>(user_emb, item_emb,
                                                                edge_buf, deg, comp,
                                                                S, U);
    } else if (ws_size >= fixed) {
        // Tier B: direct per-edge fill
        hipMemsetAsync(d_ws, 0, comp_bytes + map_bytes + deg_bytes, stream);
        claim_kernel<<<(S + 255) / 256, 256, 0, stream>>>(user_idx, item_idx,
                                                          node_map, B, U);
        fill_kernel<<<(nnz + 255) / 256, 256, 0, stream>>>(user_emb, item_emb,
                                                           adj_vals, adj_rows,
                                                           adj_cols, node_map,
                                                           deg, edge_buf, comp,
                                                           nnz, U);
        gather_kernel<<<(S * 64 + 255) / 256, 256, 0, stream>>>(user_emb, item_emb,
                                                                edge_buf, deg, comp,
                                                                S, U);
    } else {
        // Tier C: direct atomic scatter
        hipMemsetAsync(d_ws, 0, comp_bytes + map_bytes, stream);
        claim_kernel<<<(S + 255) / 256, 256, 0, stream>>>(user_idx, item_idx,
                                                          node_map, B, U);
        scatter_kernel<<<(nnz + 255) / 256, 256, 0, stream>>>(user_emb, item_emb,
                                                              adj_vals, adj_rows,
                                                              adj_cols, node_map,
                                                              comp, nnz, U);
    }
    final_kernel<<<(B * 64 + 255) / 256, 256, 0, stream>>>(user_emb, item_emb,
                                                           user_idx, item_idx,
                                                           node_map, comp, out,
                                                           B, U);
}

// Round 7
// 145.126 us; speedup vs baseline: 8.6689x; 8.6689x over previous
//
#include <hip/hip_runtime.h>

#define EMB_D 128
#define SLOT_CAP 96      // max stored edges/slot; row degree ~Poisson(32), P(>96)~0
#define FILL_CHUNK 2048  // edges per fill block
#define FILL_THREADS 256

// ---------- Pass 1: claim needed nodes. map[node] = slot+1, slot in [0,2B). ----------
__global__ void claim_kernel(const int* __restrict__ user_idx,
                             const int* __restrict__ item_idx,
                             int* __restrict__ node_map, int B, int U) {
    int t = blockIdx.x * blockDim.x + threadIdx.x;
    if (t >= 2 * B) return;
    int node = (t < B) ? user_idx[t] : (U + item_idx[t - B]);
    atomicCAS(&node_map[node], 0, t + 1);
}

__device__ __forceinline__ void slow_place_cv(int slot, int c, float v,
        float* __restrict__ comp,
        const float* __restrict__ user_emb, const float* __restrict__ item_emb,
        int U) {
    // ~never (deg > SLOT_CAP): exact fallback, comp pre-zeroed
    const float* src = (c < U) ? (user_emb + (size_t)c * EMB_D)
                               : (item_emb + (size_t)(c - U) * EMB_D);
    float* dst = comp + (size_t)slot * EMB_D;
    for (int i = 0; i < EMB_D; ++i) atomicAdd(dst + i, v * src[i]);
}

// ---------- Pass 2: LDS-staged filter + dense-flush bucketing. ----------
__global__ void __launch_bounds__(FILL_THREADS)
fill2_kernel(const float* __restrict__ user_emb,
             const float* __restrict__ item_emb,
             const float* __restrict__ vals,
             const int* __restrict__ rows,
             const int* __restrict__ cols,
             const int* __restrict__ node_map,
             int* __restrict__ deg,
             int2* __restrict__ edge_buf,
             float* __restrict__ comp,
             int nnz, int U) {
    __shared__ int  l_slot[FILL_CHUNK];
    __shared__ int2 l_cv[FILL_CHUNK];
    __shared__ int  lcount;
    const int tid = threadIdx.x;
    if (tid == 0) lcount = 0;
    __syncthreads();

    const long long base = (long long)blockIdx.x * FILL_CHUNK;
    const int K = FILL_CHUNK / FILL_THREADS;   // 8
    int r8[K];
    int s8[K];
#pragma unroll
    for (int k = 0; k < K; ++k) {              // 8 independent coalesced loads
        long long e = base + (long long)k * FILL_THREADS + tid;
        r8[k] = (e < nnz) ? rows[e] : -1;
    }
#pragma unroll
    for (int k = 0; k < K; ++k)                // 8 independent map lookups
        s8[k] = (r8[k] >= 0) ? node_map[r8[k]] : 0;
#pragma unroll
    for (int k = 0; k < K; ++k) {
        if (s8[k] != 0) {
            long long e = base + (long long)k * FILL_THREADS + tid;
            int p = atomicAdd(&lcount, 1);     // LDS atomic: block-local, cheap
            l_slot[p] = s8[k] - 1;
            l_cv[p]   = make_int2(cols[e], __float_as_int(vals[e]));
        }
    }
    __syncthreads();

    int n = lcount;
    for (int i = tid; i < n; i += FILL_THREADS) {   // dense: all lanes active
        int  slot = l_slot[i];
        int2 cv   = l_cv[i];
        int pos = atomicAdd(&deg[slot], 1);         // distributed addresses
        if (pos < SLOT_CAP)
            edge_buf[(size_t)slot * SLOT_CAP + pos] = cv;
        else
            slow_place_cv(slot, cv.x, __int_as_float(cv.y),
                          comp, user_emb, item_emb, U);
    }
}

// ---------- Pass 3 helpers ----------
__device__ __forceinline__ void gk_fetch(int j, int k, int h, int n0,
                                         int b_lo, int b_hi, float myv,
                                         const float*& pk, float& vk) {
    int jj  = j + 2 * k + h;
    int src = (jj < n0) ? jj : (n0 - 1);      // wave-uniform clamp
    int lo = __shfl(b_lo, src);
    int hi = __shfl(b_hi, src);
    float vx = __shfl(myv, src);
    vk = (jj < n0) ? vx : 0.f;                // mask tail
    pk = (const float*)((((unsigned long long)(unsigned)hi) << 32)
                        | (unsigned)lo);
}

__device__ __forceinline__ void fma4(float4& acc, float v, const float4& val) {
    acc.x = fmaf(v, val.x, acc.x);
    acc.y = fmaf(v, val.y, acc.y);
    acc.z = fmaf(v, val.z, acc.z);
    acc.w = fmaf(v, val.w, acc.w);
}

// ---------- Pass 3: one wave per slot; half-wave-per-row float4 gathers. ----------
// Edge metadata preloaded per-lane once, broadcast via shfl (no mem dependence);
// 8 gather instructions in flight, each fetching TWO 512B rows (one per half).
__global__ void __launch_bounds__(256, 1)
gather_kernel(const float* __restrict__ user_emb,
              const float* __restrict__ item_emb,
              const int2* __restrict__ edge_buf,
              const int* __restrict__ deg,
              float* __restrict__ comp,
              int nslots, int U) {
    int wid  = (blockIdx.x * blockDim.x + threadIdx.x) >> 6;
    int lane = threadIdx.x & 63;
    if (wid >= nslots) return;
    int d = deg[wid];
    bool ovf = (d > SLOT_CAP);
    int dc = ovf ? SLOT_CAP : d;
    const int2* eb = edge_buf + (size_t)wid * SLOT_CAP;
    const int h = lane >> 5;      // half id: which edge parity this lane serves
    const int q = lane & 31;      // sublane: owns dims [4q, 4q+4)

    int2 my_e = eb[lane];         // lane i owns edge i (SLOT_CAP >= 64)
    int  myc  = my_e.x;
    const float* mybase = (myc < U) ? (user_emb + (size_t)myc * EMB_D)
                                    : (item_emb + (size_t)(myc - U) * EMB_D);
    unsigned long long mba = (unsigned long long)mybase;
    int   b_lo = (int)(unsigned)mba;
    int   b_hi = (int)(mba >> 32);
    float myv  = __int_as_float(my_e.y);

    float4 a0 = {0,0,0,0}, a1 = {0,0,0,0}, a2 = {0,0,0,0}, a3 = {0,0,0,0};
    float4 a4 = {0,0,0,0}, a5 = {0,0,0,0}, a6 = {0,0,0,0}, a7 = {0,0,0,0};

    const int n0 = dc < 64 ? dc : 64;
    for (int j = 0; j < n0; j += 16) {
        const float *p0, *p1, *p2, *p3, *p4, *p5, *p6, *p7;
        float v0, v1, v2, v3, v4, v5, v6, v7;
        gk_fetch(j, 0, h, n0, b_lo, b_hi, myv, p0, v0);
        gk_fetch(j, 1, h, n0, b_lo, b_hi, myv, p1, v1);
        gk_fetch(j, 2, h, n0, b_lo, b_hi, myv, p2, v2);
        gk_fetch(j, 3, h, n0, b_lo, b_hi, myv, p3, v3);
        gk_fetch(j, 4, h, n0, b_lo, b_hi, myv, p4, v4);
        gk_fetch(j, 5, h, n0, b_lo, b_hi, myv, p5, v5);
        gk_fetch(j, 6, h, n0, b_lo, b_hi, myv, p6, v6);
        gk_fetch(j, 7, h, n0, b_lo, b_hi, myv, p7, v7);
        float4 x0 = *(const float4*)(p0 + q * 4);
        float4 x1 = *(const float4*)(p1 + q * 4);
        float4 x2 = *(const float4*)(p2 + q * 4);
        float4 x3 = *(const float4*)(p3 + q * 4);
        float4 x4 = *(const float4*)(p4 + q * 4);
        float4 x5 = *(const float4*)(p5 + q * 4);
        float4 x6 = *(const float4*)(p6 + q * 4);
        float4 x7 = *(const float4*)(p7 + q * 4);
        fma4(a0, v0, x0); fma4(a1, v1, x1); fma4(a2, v2, x2); fma4(a3, v3, x3);
        fma4(a4, v4, x4); fma4(a5, v5, x5); fma4(a6, v6, x6); fma4(a7, v7, x7);
    }

    float4 r;
    r.x = ((a0.x + a1.x) + (a2.x + a3.x)) + ((a4.x + a5.x) + (a6.x + a7.x));
    r.y = ((a0.y + a1.y) + (a2.y + a3.y)) + ((a4.y + a5.y) + (a6.y + a7.y));
    r.z = ((a0.z + a1.z) + (a2.z + a3.z)) + ((a4.z + a5.z) + (a6.z + a7.z));
    r.w = ((a0.w + a1.w) + (a2.w + a3.w)) + ((a4.w + a5.w) + (a6.w + a7.w));
    // combine the two halves: each half held edges of its parity
    r.x += __shfl_xor(r.x, 32);
    r.y += __shfl_xor(r.y, 32);
    r.z += __shfl_xor(r.z, 32);
    r.w += __shfl_xor(r.w, 32);

    // rare: degree in (64, SLOT_CAP] -> per-edge broadcast loads (halves duplicate)
    for (int j = 64; j < dc; ++j) {
        int2 ed = eb[j];
        int c = ed.x;
        float v = __int_as_float(ed.y);
        const float* src = (c < U) ? (user_emb + (size_t)c * EMB_D)
                                   : (item_emb + (size_t)(c - U) * EMB_D);
        float4 xx = *(const float4*)(src + q * 4);
        fma4(r, v, xx);
    }

    if (h == 0) {
        float4* dst = (float4*)(comp + (size_t)wid * EMB_D) + q;
        if (ovf) {  // overflow part already added atomically into comp
            float4 o = *dst;
            r.x += o.x; r.y += o.y; r.z += o.z; r.w += o.w;
        }
        *dst = r;   // includes d==0 -> store zeros
    }
}

// ---------- Pass 4: per-pair fused gather + dot. One wave per output. ----------
__global__ void final_kernel(const float* __restrict__ user_emb,
                             const float* __restrict__ item_emb,
                             const int* __restrict__ user_idx,
                             const int* __restrict__ item_idx,
                             const int* __restrict__ node_map,
                             const float* __restrict__ comp,
                             float* __restrict__ out, int B, int U) {
    int wid  = (blockIdx.x * blockDim.x + threadIdx.x) >> 6;
    int lane = threadIdx.x & 63;
    if (wid >= B) return;
    int un  = user_idx[wid];
    int inn = item_idx[wid];
    int su  = node_map[un] - 1;
    int si  = node_map[U + inn] - 1;
    float2 eu = *(const float2*)(user_emb + (size_t)un * EMB_D + lane * 2);
    float2 ei = *(const float2*)(item_emb + (size_t)inn * EMB_D + lane * 2);
    float2 cu = *(const float2*)(comp + (size_t)su * EMB_D + lane * 2);
    float2 ci = *(const float2*)(comp + (size_t)si * EMB_D + lane * 2);
    float p = (eu.x + cu.x) * (ei.x + ci.x) + (eu.y + cu.y) * (ei.y + ci.y);
#pragma unroll
    for (int off = 32; off; off >>= 1) p += __shfl_down(p, off);
    if (lane == 0) out[wid] = 0.25f * p;
}

// ---------- Fallback (tiny ws): direct atomic scatter ----------
__global__ void scatter_kernel(const float* __restrict__ user_emb,
                               const float* __restrict__ item_emb,
                               const float* __restrict__ vals,
                               const int* __restrict__ rows,
                               const int* __restrict__ cols,
                               const int* __restrict__ node_map,
                               float* __restrict__ comp,
                               int nnz, int U) {
    int e = blockIdx.x * blockDim.x + threadIdx.x;
    int lane = threadIdx.x & 63;
    int s = 0; int c = 0; float v = 0.f;
    if (e < nnz) {
        int r = rows[e];
        s = node_map[r];
        if (s != 0) { c = cols[e]; v = vals[e]; }
    }
    unsigned long long mask = __ballot(s != 0);
    while (mask) {
        int j = __ffsll((long long)mask) - 1;
        mask &= mask - 1;
        int   cj    = __shfl(c, j);
        float vj    = __shfl(v, j);
        int   slotj = __shfl(s, j) - 1;
        const float* src = (cj < U) ? (user_emb + (size_t)cj * EMB_D)
                                    : (item_emb + (size_t)(cj - U) * EMB_D);
        float2 xx = *(const float2*)(src + lane * 2);
        float* dst = comp + (size_t)slotj * EMB_D + lane * 2;
        atomicAdd(dst,     xx.x * vj);
        atomicAdd(dst + 1, xx.y * vj);
    }
}

extern "C" void kernel_launch(void* const* d_in, const int* in_sizes, int n_in,
                              void* d_out, int out_size, void* d_ws, size_t ws_size,
                              hipStream_t stream) {
    const float* user_emb = (const float*)d_in[0];
    const float* item_emb = (const float*)d_in[1];
    const float* adj_vals = (const float*)d_in[2];
    const int*   adj_rows = (const int*)d_in[3];
    const int*   adj_cols = (const int*)d_in[4];
    const int*   user_idx = (const int*)d_in[5];
    const int*   item_idx = (const int*)d_in[6];
    float* out = (float*)d_out;

    int U   = in_sizes[0] / EMB_D;
    int I   = in_sizes[1] / EMB_D;
    int N   = U + I;
    int nnz = in_sizes[2];
    int B   = in_sizes[5];
    int S   = 2 * B;                       // slot count

    // Workspace layout: [comp S*D f32][node_map N i32][deg S i32][edge_buf S*CAP int2]
    size_t comp_bytes = (size_t)S * EMB_D * sizeof(float);
    size_t map_bytes  = ((size_t)N * sizeof(int) + 15) & ~(size_t)15;
    size_t deg_bytes  = (((size_t)S) * sizeof(int) + 15) & ~(size_t)15;
    size_t edge_bytes = (size_t)S * SLOT_CAP * sizeof(int2);
    size_t fixed      = comp_bytes + map_bytes + deg_bytes + edge_bytes;

    float* comp     = (float*)d_ws;
    int*   node_map = (int*)((char*)d_ws + comp_bytes);
    int*   deg      = (int*)((char*)d_ws + comp_bytes + map_bytes);
    int2*  edge_buf = (int2*)((char*)d_ws + comp_bytes + map_bytes + deg_bytes);

    if (ws_size >= fixed) {
        // comp must be zero before fill (overflow fallback atomics land there).
        hipMemsetAsync(d_ws, 0, comp_bytes + map_bytes + deg_bytes, stream);
        claim_kernel<<<(S + 255) / 256, 256, 0, stream>>>(user_idx, item_idx,
                                                          node_map, B, U);
        int fill_blocks = (int)((nnz + FILL_CHUNK - 1) / FILL_CHUNK);
        fill2_kernel<<<fill_blocks, FILL_THREADS, 0, stream>>>(
            user_emb, item_emb, adj_vals, adj_rows, adj_cols, node_map,
            deg, edge_buf, comp, nnz, U);
        gather_kernel<<<(S * 64 + 255) / 256, 256, 0, stream>>>(user_emb, item_emb,
                                                                edge_buf, deg, comp,
                                                                S, U);
    } else {
        hipMemsetAsync(d_ws, 0, comp_bytes + map_bytes, stream);
        claim_kernel<<<(S + 255) / 256, 256, 0, stream>>>(user_idx, item_idx,
                                                          node_map, B, U);
        scatter_kernel<<<(nnz + 255) / 256, 256, 0, stream>>>(user_emb, item_emb,
                                                              adj_vals, adj_rows,
                                                              adj_cols, node_map,
                                                              comp, nnz, U);
    }
    final_kernel<<<(B * 64 + 255) / 256, 256, 0, stream>>>(user_emb, item_emb,
                                                           user_idx, item_idx,
                                                           node_map, comp, out,
                                                           B, U);
}

// Round 8
// 136.731 us; speedup vs baseline: 9.2012x; 1.0614x over previous
//
#include <hip/hip_runtime.h>

#define EMB_D 128
#define SLOT_CAP 96      // max stored edges/slot; row degree ~Poisson(32), P(>96)~0

// ---------- Pass 1: claim needed nodes. map[node] = slot+1, slot in [0,2B). ----------
__global__ void claim_kernel(const int* __restrict__ user_idx,
                             const int* __restrict__ item_idx,
                             int* __restrict__ node_map, int B, int U) {
    int t = blockIdx.x * blockDim.x + threadIdx.x;
    if (t >= 2 * B) return;
    int node = (t < B) ? user_idx[t] : (U + item_idx[t - B]);
    atomicCAS(&node_map[node], 0, t + 1);
}

// ---------- Pass 2: bucket filtered edges into per-slot lists (R3 structure). ----------
__global__ void fill_kernel(const float* __restrict__ user_emb,
                            const float* __restrict__ item_emb,
                            const float* __restrict__ vals,
                            const int* __restrict__ rows,
                            const int* __restrict__ cols,
                            const int* __restrict__ node_map,
                            int* __restrict__ deg,
                            int2* __restrict__ edge_buf,
                            float* __restrict__ comp,
                            int nnz, int U) {
    int e = blockIdx.x * blockDim.x + threadIdx.x;
    if (e >= nnz) return;
    int s = node_map[rows[e]];
    if (s == 0) return;
    int slot = s - 1;
    int c = cols[e];                 // issue before the atomic: overlap latency
    float v = vals[e];
    int pos = atomicAdd(&deg[slot], 1);
    if (pos < SLOT_CAP) {
        edge_buf[(size_t)slot * SLOT_CAP + pos] = make_int2(c, __float_as_int(v));
    } else {  // ~never: exact fallback, comp pre-zeroed
        const float* src = (c < U) ? (user_emb + (size_t)c * EMB_D)
                                   : (item_emb + (size_t)(c - U) * EMB_D);
        float* dst = comp + (size_t)slot * EMB_D;
        for (int i = 0; i < EMB_D; ++i) atomicAdd(dst + i, v * src[i]);
    }
}

__device__ __forceinline__ void fma4(float4& acc, float v, const float4& val) {
    acc.x = fmaf(v, val.x, acc.x);
    acc.y = fmaf(v, val.y, acc.y);
    acc.z = fmaf(v, val.z, acc.z);
    acc.w = fmaf(v, val.w, acc.w);
}

// ---------- Pass 3: one wave per slot; half-wave-per-row float4 gathers. ----------
// Edge metadata preloaded per-lane once, broadcast via shfl (register-only);
// 8 load instructions (16 rows) forced in flight via sched_barrier.
__global__ void __launch_bounds__(256)
gather_kernel(const float* __restrict__ user_emb,
              const float* __restrict__ item_emb,
              const int2* __restrict__ edge_buf,
              const int* __restrict__ deg,
              float* __restrict__ comp,
              int nslots, int U) {
    int wid  = (blockIdx.x * blockDim.x + threadIdx.x) >> 6;
    int lane = threadIdx.x & 63;
    if (wid >= nslots) return;
    int d = deg[wid];
    bool ovf = (d > SLOT_CAP);
    int dc = ovf ? SLOT_CAP : d;
    const int2* eb = edge_buf + (size_t)wid * SLOT_CAP;
    const int h = lane >> 5;      // half id: edge parity this lane serves
    const int q = lane & 31;      // sublane: owns dims [4q, 4q+4)

    int2 my_e = eb[lane];         // lane i owns edge i (SLOT_CAP >= 64)
    int  myc  = my_e.x;
    const float* mybase = (myc < U) ? (user_emb + (size_t)myc * EMB_D)
                                    : (item_emb + (size_t)(myc - U) * EMB_D);
    unsigned long long mba = (unsigned long long)mybase;
    int   b_lo = (int)(unsigned)mba;
    int   b_hi = (int)(mba >> 32);
    float myv  = __int_as_float(my_e.y);

    float4 acc0 = {0.f, 0.f, 0.f, 0.f};
    float4 acc1 = {0.f, 0.f, 0.f, 0.f};

    const int n0 = dc < 64 ? dc : 64;
    for (int j = 0; j < n0; j += 16) {
        const float* p[8];
        float vv[8];
#pragma unroll
        for (int k = 0; k < 8; ++k) {           // register-only shfl broadcast
            int jj   = j + 2 * k + h;
            int srcl = (jj < n0) ? jj : 0;      // lane 0 always valid (n0 > 0 here)
            int lo = __shfl(b_lo, srcl);
            int hi = __shfl(b_hi, srcl);
            float vx = __shfl(myv, srcl);
            vv[k] = (jj < n0) ? vx : 0.f;       // mask tail contribution
            p[k]  = (const float*)((((unsigned long long)(unsigned)hi) << 32)
                                   | (unsigned)lo);
        }
        float4 x[8];
#pragma unroll
        for (int k = 0; k < 8; ++k)             // 8 independent 512B-row loads
            x[k] = *(const float4*)(p[k] + q * 4);
        __builtin_amdgcn_sched_barrier(0);      // keep all 8 in flight
#pragma unroll
        for (int k = 0; k < 8; ++k)
            fma4((k & 1) ? acc1 : acc0, vv[k], x[k]);
    }

    float4 r;
    r.x = acc0.x + acc1.x;
    r.y = acc0.y + acc1.y;
    r.z = acc0.z + acc1.z;
    r.w = acc0.w + acc1.w;
    // combine the two halves: each half held edges of its parity
    r.x += __shfl_xor(r.x, 32);
    r.y += __shfl_xor(r.y, 32);
    r.z += __shfl_xor(r.z, 32);
    r.w += __shfl_xor(r.w, 32);

    // rare: degree in (64, SLOT_CAP] -> per-edge broadcast loads (halves duplicate,
    // so only half h==0 accumulates; h==1 lanes' r is discarded at the store)
    if (h == 0) {
        for (int j = 64; j < dc; ++j) {
            int2 ed = eb[j];
            int c = ed.x;
            float v = __int_as_float(ed.y);
            const float* src = (c < U) ? (user_emb + (size_t)c * EMB_D)
                                       : (item_emb + (size_t)(c - U) * EMB_D);
            float4 xx = *(const float4*)(src + q * 4);
            fma4(r, v, xx);
        }
        float4* dst = (float4*)(comp + (size_t)wid * EMB_D) + q;
        if (ovf) {  // overflow part already added atomically into comp
            float4 o = *dst;
            r.x += o.x; r.y += o.y; r.z += o.z; r.w += o.w;
        }
        *dst = r;   // includes d==0 -> store zeros
    }
}

// ---------- Pass 4: per-pair fused gather + dot. One wave per output. ----------
__global__ void final_kernel(const float* __restrict__ user_emb,
                             const float* __restrict__ item_emb,
                             const int* __restrict__ user_idx,
                             const int* __restrict__ item_idx,
                             const int* __restrict__ node_map,
                             const float* __restrict__ comp,
                             float* __restrict__ out, int B, int U) {
    int wid  = (blockIdx.x * blockDim.x + threadIdx.x) >> 6;
    int lane = threadIdx.x & 63;
    if (wid >= B) return;
    int un  = user_idx[wid];
    int inn = item_idx[wid];
    int su  = node_map[un] - 1;
    int si  = node_map[U + inn] - 1;
    float2 eu = *(const float2*)(user_emb + (size_t)un * EMB_D + lane * 2);
    float2 ei = *(const float2*)(item_emb + (size_t)inn * EMB_D + lane * 2);
    float2 cu = *(const float2*)(comp + (size_t)su * EMB_D + lane * 2);
    float2 ci = *(const float2*)(comp + (size_t)si * EMB_D + lane * 2);
    float p = (eu.x + cu.x) * (ei.x + ci.x) + (eu.y + cu.y) * (ei.y + ci.y);
#pragma unroll
    for (int off = 32; off; off >>= 1) p += __shfl_down(p, off);
    if (lane == 0) out[wid] = 0.25f * p;
}

// ---------- Fallback (tiny ws): direct atomic scatter ----------
__global__ void scatter_kernel(const float* __restrict__ user_emb,
                               const float* __restrict__ item_emb,
                               const float* __restrict__ vals,
                               const int* __restrict__ rows,
                               const int* __restrict__ cols,
                               const int* __restrict__ node_map,
                               float* __restrict__ comp,
                               int nnz, int U) {
    int e = blockIdx.x * blockDim.x + threadIdx.x;
    int lane = threadIdx.x & 63;
    int s = 0; int c = 0; float v = 0.f;
    if (e < nnz) {
        int r = rows[e];
        s = node_map[r];
        if (s != 0) { c = cols[e]; v = vals[e]; }
    }
    unsigned long long mask = __ballot(s != 0);
    while (mask) {
        int j = __ffsll((long long)mask) - 1;
        mask &= mask - 1;
        int   cj    = __shfl(c, j);
        float vj    = __shfl(v, j);
        int   slotj = __shfl(s, j) - 1;
        const float* src = (cj < U) ? (user_emb + (size_t)cj * EMB_D)
                                    : (item_emb + (size_t)(cj - U) * EMB_D);
        float2 xx = *(const float2*)(src + lane * 2);
        float* dst = comp + (size_t)slotj * EMB_D + lane * 2;
        atomicAdd(dst,     xx.x * vj);
        atomicAdd(dst + 1, xx.y * vj);
    }
}

extern "C" void kernel_launch(void* const* d_in, const int* in_sizes, int n_in,
                              void* d_out, int out_size, void* d_ws, size_t ws_size,
                              hipStream_t stream) {
    const float* user_emb = (const float*)d_in[0];
    const float* item_emb = (const float*)d_in[1];
    const float* adj_vals = (const float*)d_in[2];
    const int*   adj_rows = (const int*)d_in[3];
    const int*   adj_cols = (const int*)d_in[4];
    const int*   user_idx = (const int*)d_in[5];
    const int*   item_idx = (const int*)d_in[6];
    float* out = (float*)d_out;

    int U   = in_sizes[0] / EMB_D;
    int I   = in_sizes[1] / EMB_D;
    int N   = U + I;
    int nnz = in_sizes[2];
    int B   = in_sizes[5];
    int S   = 2 * B;                       // slot count

    // Workspace layout: [comp S*D f32][node_map N i32][deg S i32][edge_buf S*CAP int2]
    size_t comp_bytes = (size_t)S * EMB_D * sizeof(float);
    size_t map_bytes  = ((size_t)N * sizeof(int) + 15) & ~(size_t)15;
    size_t deg_bytes  = (((size_t)S) * sizeof(int) + 15) & ~(size_t)15;
    size_t edge_bytes = (size_t)S * SLOT_CAP * sizeof(int2);
    size_t fixed      = comp_bytes + map_bytes + deg_bytes + edge_bytes;

    float* comp     = (float*)d_ws;
    int*   node_map = (int*)((char*)d_ws + comp_bytes);
    int*   deg      = (int*)((char*)d_ws + comp_bytes + map_bytes);
    int2*  edge_buf = (int2*)((char*)d_ws + comp_bytes + map_bytes + deg_bytes);

    if (ws_size >= fixed) {
        // comp must be zero before fill (overflow fallback atomics land there).
        hipMemsetAsync(d_ws, 0, comp_bytes + map_bytes + deg_bytes, stream);
        claim_kernel<<<(S + 255) / 256, 256, 0, stream>>>(user_idx, item_idx,
                                                          node_map, B, U);
        fill_kernel<<<(nnz + 255) / 256, 256, 0, stream>>>(user_emb, item_emb,
                                                           adj_vals, adj_rows,
                                                           adj_cols, node_map,
                                                           deg, edge_buf, comp,
                                                           nnz, U);
        gather_kernel<<<(S * 64 + 255) / 256, 256, 0, stream>>>(user_emb, item_emb,
                                                                edge_buf, deg, comp,
                                                                S, U);
    } else {
        hipMemsetAsync(d_ws, 0, comp_bytes + map_bytes, stream);
        claim_kernel<<<(S + 255) / 256, 256, 0, stream>>>(user_idx, item_idx,
                                                          node_map, B, U);
        scatter_kernel<<<(nnz + 255) / 256, 256, 0, stream>>>(user_emb, item_emb,
                                                              adj_vals, adj_rows,
                                                              adj_cols, node_map,
                                                              comp, nnz, U);
    }
    final_kernel<<<(B * 64 + 255) / 256, 256, 0, stream>>>(user_emb, item_emb,
                                                           user_idx, item_idx,
                                                           node_map, comp, out,
                                                           B, U);
}